// Round 3
// baseline (725.431 us; speedup 1.0000x reference)
//
#include <hip/hip_runtime.h>
#include <hip/hip_bf16.h>

#define DEV static __device__ __forceinline__

constexpr int F1 = 128;   // input features
constexpr int H1 = 8;     // heads layer1
constexpr int C  = 64;    // channels per head
constexpr int B  = 64;    // graphs
constexpr int K  = 10;    // classes
constexpr float NEG = 0.2f;

typedef __attribute__((ext_vector_type(8))) short short8;
typedef __attribute__((ext_vector_type(4))) float floatx4;
typedef __attribute__((ext_vector_type(2))) float floatx2;

DEV float b2f(__hip_bfloat16 x) { return __bfloat162float(x); }
DEV float elu1(float v) { return v > 0.f ? v : (__expf(v) - 1.f); }
DEV unsigned short f2bbits(float f) {
  __hip_bfloat16 b = __float2bfloat16(f);
  return *(unsigned short*)&b;
}
DEV float blo(unsigned u) { return __uint_as_float(u << 16); }
DEV float bhi(unsigned u) { return __uint_as_float(u & 0xffff0000u); }
DEV float bu(unsigned short u) { return __uint_as_float(((unsigned)u) << 16); }
DEV unsigned pack2(float lo, float hi) {
  return (unsigned)f2bbits(lo) | ((unsigned)f2bbits(hi) << 16);
}
// 1/x via v_rcp_f32 + one Newton step
DEV float rcp_nr(float x) {
  float r = __builtin_amdgcn_rcpf(x);
  return r * (2.f - x * r);
}
// acc(pair of features) += x(pair) * w(broadcast pair held in SGPRs)
DEV void pk_fma(floatx2& acc, floatx2 x, floatx2 w) {
  asm("v_pk_fma_f32 %0, %1, %2, %0" : "+v"(acc) : "v"(x), "s"(w));
}
DEV void pk_add(floatx2& acc, floatx2 w) {
  asm("v_pk_add_f32 %0, %0, %1" : "+v"(acc) : "s"(w));
}

// out1 PERMUTED layout: position p = hp*128 + l16*8 + nt  <->  natural channel
// c = hp*128 + nt*16 + l16. W2frag k-rows and b1 permuted to match.
// W1frag k-rows use the EVEN/ODD feature permutation: frag k-position kp holds
// natural input channel knat(kp) = kp<64 ? 2*kp : 2*(kp-64)+1, matching the
// LDS aggregate layout written by aggx phase 1 (lo feats at 0..63, hi at 64..127).

// Self-detection: thread 0 samples 128 even-index bf16 reinterps of x.
DEV int detect_dev(const void* xraw, int* lds) {
  if (threadIdx.x == 0) {
    const __hip_bfloat16* xb = (const __hip_bfloat16*)xraw;
    int bad = 0;
    for (int i = 0; i < 128; ++i) {
      float v = b2f(xb[2 * i]);
      if (!(fabsf(v) < 1e4f)) bad++;
    }
    *lds = (bad < 13) ? 1 : 0;     // 1 = bf16, 0 = f32
  }
  __syncthreads();
  return *lds;
}

#define CVT(p, i) (isbf ? b2f(((const __hip_bfloat16*)(p))[i]) : ((const float*)(p))[i])

// ---------- fused prep ----------
__global__ void fused_prep_kernel(const void* x_raw, const void* w1raw,
                                  const void* as1r, const void* ad1r, const void* b1r,
                                  const void* w2raw,
                                  const void* as2r, const void* ad2r, const void* b2r,
                                  const void* l1wr, const void* l1br,
                                  const void* l2wr, const void* l2br,
                                  unsigned short* __restrict__ xbf,
                                  unsigned short* __restrict__ w1frag,
                                  unsigned short* __restrict__ w2frag,
                                  unsigned short* __restrict__ vfrag,
                                  float* __restrict__ wts,
                                  int* __restrict__ deg,
                                  float* __restrict__ pooled,
                                  int nX, int N) {
  __shared__ int fl;
  int isbf = detect_dev(x_raw, &fl);
  int gid = blockIdx.x * 256 + threadIdx.x;
  int stride = gridDim.x * 256;

  if (isbf) {
    const unsigned short* src = (const unsigned short*)x_raw;
    for (int i = gid; i < nX; i += stride) xbf[i] = src[i];
  } else {
    const float* src = (const float*)x_raw;
    for (int i = gid; i < nX; i += stride) xbf[i] = f2bbits(src[i]);
  }
  // b1 stored PERMUTED: wts[1024 + p] = b1[c_nat(p)]
  for (int i = gid; i < 512;  i += stride) {
    int hp = i >> 7, l16 = (i >> 3) & 15, nt = i & 7;
    int c = hp * 128 + nt * 16 + l16;
    wts[1024 + i] = CVT(b1r, c);
  }
  for (int i = gid; i < 64;   i += stride) wts[1536 + i] = CVT(as2r, i);
  for (int i = gid; i < 64;   i += stride) wts[1600 + i] = CVT(ad2r, i);
  for (int i = gid; i < 64;   i += stride) wts[1664 + i] = CVT(b2r, i);
  for (int i = gid; i < 4096; i += stride) wts[1728 + i] = CVT(l1wr, i);
  for (int i = gid; i < 64;   i += stride) wts[5824 + i] = CVT(l1br, i);
  for (int i = gid; i < 640;  i += stride) wts[5888 + i] = CVT(l2wr, i);
  for (int i = gid; i < 10;   i += stride) wts[6528 + i] = CVT(l2br, i);
  // W1frag with EVEN/ODD-permuted k to match aggx LDS aggregate layout
  for (int t = gid; t < 8192; t += stride) {
    int lane = t & 63, ks = (t >> 6) & 3, nt = t >> 8;
    for (int j = 0; j < 8; ++j) {
      int kp = ks * 32 + (lane >> 4) * 8 + j;
      int k = (kp < 64) ? (2 * kp) : (2 * (kp - 64) + 1);
      int n = nt * 16 + (lane & 15);
      w1frag[t * 8 + j] = f2bbits(CVT(w1raw, k * 512 + n));
    }
  }
  // W2frag with PERMUTED k: k index in fragment = position p; fetch W2[c_nat(p)]
  for (int t = gid; t < 4096; t += stride) {
    int lane = t & 63, nt = (t >> 6) & 3, ks = t >> 8;
    for (int j = 0; j < 8; ++j) {
      int p = ks * 32 + (lane >> 4) * 8 + j;          // permuted position
      int hp = p >> 7, pl16 = (p >> 3) & 15, pnt = p & 7;
      int k = hp * 128 + pnt * 16 + pl16;             // natural channel
      int n = nt * 16 + (lane & 15);
      w2frag[t * 8 + j] = f2bbits(CVT(w2raw, k * 64 + n));
    }
  }
  // Vfrag: B-fragment of V[128 x 16] (natural k; used with xbf directly)
  for (int t = gid; t < 2048; t += stride) {
    int j = t & 7, lane = (t >> 3) & 63, ks = t >> 9;
    int k = ks * 32 + (lane >> 4) * 8 + j;
    int n = lane & 15;
    int hh = (n < 8) ? n : (n - 8);
    float s = 0.f;
    if (n < 8) {
      for (int c = 0; c < 64; ++c)
        s += CVT(w1raw, k * 512 + hh * 64 + c) * CVT(as1r, hh * 64 + c);
    } else {
      for (int c = 0; c < 64; ++c)
        s += CVT(w1raw, k * 512 + hh * 64 + c) * CVT(ad1r, hh * 64 + c);
    }
    vfrag[(ks * 64 + lane) * 8 + j] = f2bbits(s);
  }
  for (int i = gid; i < N; i += stride) deg[i] = 0;
  for (int i = gid; i < B * C; i += stride) pooled[i] = 0.f;
}

// ---------- degree count ----------
__global__ void deg_count_kernel(const int* __restrict__ ei, int E, int Etot,
                                 int* __restrict__ deg) {
  int e = blockIdx.x * blockDim.x + threadIdx.x;
  if (e >= Etot) return;
  int d = (e < E) ? ei[E + e] : e - E;
  atomicAdd(&deg[d], 1);
}

// ---------- CSR scans ----------
__global__ void scan_block_kernel(const int* __restrict__ deg,
                                  int* __restrict__ local,
                                  int* __restrict__ bsum, int N) {
  __shared__ int tmp[256];
  int t = threadIdx.x;
  int i = blockIdx.x * 256 + t;
  int v = (i < N) ? deg[i] : 0;
  tmp[t] = v;
  __syncthreads();
  for (int off = 1; off < 256; off <<= 1) {
    int u = (t >= off) ? tmp[t - off] : 0;
    __syncthreads();
    tmp[t] += u;
    __syncthreads();
  }
  if (i < N) local[i] = tmp[t] - v;
  if (t == 255) bsum[blockIdx.x] = tmp[255];
}

__global__ void scan_finish_kernel(const int* __restrict__ local,
                                   const int* __restrict__ bsum, int nb,
                                   int* __restrict__ rowptr,
                                   int* __restrict__ cursor, int N, int Etot) {
  __shared__ int tmp[256];
  __shared__ int offs;
  int t = threadIdx.x;
  int v0 = (t < nb) ? bsum[t] : 0;
  tmp[t] = v0;
  __syncthreads();
  for (int off = 1; off < 256; off <<= 1) {
    int u = (t >= off) ? tmp[t - off] : 0;
    __syncthreads();
    tmp[t] += u;
    __syncthreads();
  }
  if (t == (int)blockIdx.x) offs = tmp[t] - v0;
  __syncthreads();
  int i = blockIdx.x * 256 + t;
  if (i < N) {
    int r = local[i] + offs;
    rowptr[i] = r;
    cursor[i] = r;
  }
  if (i == 0) rowptr[N] = Etot;
}

// ---------- attention scalars: a_s/a_d = x @ V  (4 MFMA per 16 rows) ----------
__global__ __launch_bounds__(256) void att_scalars_kernel(
    const unsigned short* __restrict__ xbf,     // N x 128 bf16
    const unsigned short* __restrict__ vfrag,   // [4ks][64][8] bf16
    float* __restrict__ a_s, float* __restrict__ a_d,   // N x 8
    int N) {
  int t = threadIdx.x, w = t >> 6, lane = t & 63;
  int quad = lane >> 4, l16 = lane & 15;
  int row0 = blockIdx.x * 64 + w * 16;

  floatx4 acc = {};
  int rl = row0 + l16; if (rl >= N) rl = N - 1;
  const unsigned short* xp = xbf + (size_t)rl * 128 + quad * 8;
#pragma unroll
  for (int ks = 0; ks < 4; ++ks) {
    short8 a = *(const short8*)(xp + ks * 32);
    short8 b = *(const short8*)&vfrag[(ks * 64 + lane) * 8];
    acc = __builtin_amdgcn_mfma_f32_16x16x32_bf16(a, b, acc, 0, 0, 0);
  }
#pragma unroll
  for (int r = 0; r < 4; ++r) {
    int row = row0 + quad * 4 + r;
    if (row < N) {
      if (l16 < 8) a_s[(size_t)row * 8 + l16] = acc[r];
      else         a_d[(size_t)row * 8 + (l16 - 8)] = acc[r];
    }
  }
}

// ---------- CSR fill + per-edge softmax weights (f32, CSR slot order) ----------
__global__ void fill_weight_kernel(const int* __restrict__ ei, int E, int Etot,
                                   const float* __restrict__ a_s,
                                   const float* __restrict__ a_d,
                                   int* __restrict__ cursor,
                                   int* __restrict__ col,
                                   float* __restrict__ wedge) {
  int e = blockIdx.x * 256 + threadIdx.x;
  if (e >= Etot) return;
  int s, d;
  if (e < E) { s = ei[e]; d = ei[E + e]; } else { s = d = e - E; }
  int pos = atomicAdd(&cursor[d], 1);
  col[pos] = s;
  float4 s0 = *(const float4*)(a_s + (size_t)s * 8);
  float4 s1 = *(const float4*)(a_s + (size_t)s * 8 + 4);
  float4 d0 = *(const float4*)(a_d + (size_t)d * 8);
  float4 d1 = *(const float4*)(a_d + (size_t)d * 8 + 4);
  float4 w0, w1;
  float v;
  v = s0.x + d0.x; v = v > 0.f ? v : NEG * v; w0.x = __expf(v);
  v = s0.y + d0.y; v = v > 0.f ? v : NEG * v; w0.y = __expf(v);
  v = s0.z + d0.z; v = v > 0.f ? v : NEG * v; w0.z = __expf(v);
  v = s0.w + d0.w; v = v > 0.f ? v : NEG * v; w0.w = __expf(v);
  v = s1.x + d1.x; v = v > 0.f ? v : NEG * v; w1.x = __expf(v);
  v = s1.y + d1.y; v = v > 0.f ? v : NEG * v; w1.y = __expf(v);
  v = s1.z + d1.z; v = v > 0.f ? v : NEG * v; w1.z = __expf(v);
  v = s1.w + d1.w; v = v > 0.f ? v : NEG * v; w1.w = __expf(v);
  *(float4*)(wedge + (size_t)pos * 8)     = w0;
  *(float4*)(wedge + (size_t)pos * 8 + 4) = w1;
}

// ---------- fused x-space aggregation + W1 MFMA + bias/ELU -> out1 ----------
// Block = 512 threads (8 waves), 8 dests. Phase 1 is EDGE-BALANCED: the
// block's contiguous CSR range [rowptr[dbase], rowptr[dbase+8]) is split
// evenly across the 8 waves; each wave accumulates weighted x rows in
// registers and flushes partial sums into an LDS f32 aggregate (ds_add_f32)
// at dest boundaries (~2 flushes/wave). Removes the max-degree critical path.
// Phase 2: normalize + pack from LDS, per-head [16x128]@[128x512] MFMA GEMM.
__global__ __launch_bounds__(512, 8) void aggx_gemm1_kernel(
    const unsigned short* __restrict__ xbf,     // N x 128 bf16
    const unsigned short* __restrict__ W1frag,  // [32][4][64][8] bf16 (even/odd k)
    const int* __restrict__ rowptr,
    const int* __restrict__ col,
    const float* __restrict__ wedge,            // Etot x 8 f32 (CSR order)
    const float* __restrict__ bias_perm,        // 512, PERMUTED
    unsigned short* __restrict__ out1,          // N x 512 bf16 (PERMUTED)
    int N) {
  // AggF[h][d][slot]: slot l<64 = channel 2l, slot 64+l = channel 2l+1.
  // stride 132 f32 (528B, 16B-aligned) de-phases phase-2 reads across banks.
  __shared__ float AggF[8 * 8 * 132];
  __shared__ float DN[64];                      // [h*8+d]
  int t = threadIdx.x;
  int w = __builtin_amdgcn_readfirstlane(t >> 6);  // force wave-uniform
  int lane = t & 63;
  int dbase = blockIdx.x * 8;
  const unsigned* xd = (const unsigned*)xbf;

  for (int k = t; k < 8 * 8 * 132; k += 512) AggF[k] = 0.f;
  if (t < 64) DN[t] = 0.f;
  __syncthreads();

  // ---- phase 1: balanced edge chunks ----
  {
    int R0 = rowptr[dbase];
    int R8 = rowptr[min(dbase + 8, N)];
    int L  = R8 - R0;
    int CH = (L + 7) >> 3;
    int ib = R0 + w * CH;
    int ie = min(ib + CH, R8);
    if (ib < ie) {
      int d = 0;
      while (d < 7 && rowptr[min(dbase + d + 1, N)] <= ib) ++d;
      int nxt = rowptr[min(dbase + d + 1, N)];
      floatx2 a0 = {}, a1 = {}, a2 = {}, a3 = {};
      floatx2 a4 = {}, a5 = {}, a6 = {}, a7 = {};
      floatx2 dn01 = {}, dn23 = {}, dn45 = {}, dn67 = {};
      bool touched = false;
      auto flush = [&](int dc) {
        atomicAdd(&AggF[(0 * 8 + dc) * 132 + lane], a0.x);
        atomicAdd(&AggF[(0 * 8 + dc) * 132 + 64 + lane], a0.y);
        atomicAdd(&AggF[(1 * 8 + dc) * 132 + lane], a1.x);
        atomicAdd(&AggF[(1 * 8 + dc) * 132 + 64 + lane], a1.y);
        atomicAdd(&AggF[(2 * 8 + dc) * 132 + lane], a2.x);
        atomicAdd(&AggF[(2 * 8 + dc) * 132 + 64 + lane], a2.y);
        atomicAdd(&AggF[(3 * 8 + dc) * 132 + lane], a3.x);
        atomicAdd(&AggF[(3 * 8 + dc) * 132 + 64 + lane], a3.y);
        atomicAdd(&AggF[(4 * 8 + dc) * 132 + lane], a4.x);
        atomicAdd(&AggF[(4 * 8 + dc) * 132 + 64 + lane], a4.y);
        atomicAdd(&AggF[(5 * 8 + dc) * 132 + lane], a5.x);
        atomicAdd(&AggF[(5 * 8 + dc) * 132 + 64 + lane], a5.y);
        atomicAdd(&AggF[(6 * 8 + dc) * 132 + lane], a6.x);
        atomicAdd(&AggF[(6 * 8 + dc) * 132 + 64 + lane], a6.y);
        atomicAdd(&AggF[(7 * 8 + dc) * 132 + lane], a7.x);
        atomicAdd(&AggF[(7 * 8 + dc) * 132 + 64 + lane], a7.y);
        if (lane == 0) {
          atomicAdd(&DN[0 * 8 + dc], dn01.x);
          atomicAdd(&DN[1 * 8 + dc], dn01.y);
          atomicAdd(&DN[2 * 8 + dc], dn23.x);
          atomicAdd(&DN[3 * 8 + dc], dn23.y);
          atomicAdd(&DN[4 * 8 + dc], dn45.x);
          atomicAdd(&DN[5 * 8 + dc], dn45.y);
          atomicAdd(&DN[6 * 8 + dc], dn67.x);
          atomicAdd(&DN[7 * 8 + dc], dn67.y);
        }
      };
      auto zero = [&]() {
        a0 = a1 = a2 = a3 = a4 = a5 = a6 = a7 = (floatx2){0.f, 0.f};
        dn01 = dn23 = dn45 = dn67 = (floatx2){0.f, 0.f};
      };
      for (int i = ib; i < ie; ++i) {
        while (i >= nxt) {
          if (touched) { flush(d); zero(); touched = false; }
          ++d;
          nxt = rowptr[min(dbase + d + 1, N)];
        }
        int s = __builtin_amdgcn_readfirstlane(col[i]);
        const float* wp = wedge + (size_t)i * 8;
        float w0 = wp[0], w1 = wp[1], w2 = wp[2], w3 = wp[3];
        float w4 = wp[4], w5 = wp[5], w6 = wp[6], w7 = wp[7];
        floatx2 p01 = {w0, w1}, p23 = {w2, w3}, p45 = {w4, w5}, p67 = {w6, w7};
        pk_add(dn01, p01); pk_add(dn23, p23);
        pk_add(dn45, p45); pk_add(dn67, p67);
        unsigned xv = xd[((size_t)s << 6) + lane];
        floatx2 xp; xp.x = blo(xv); xp.y = bhi(xv);
        floatx2 b0 = {w0, w0}, b1 = {w1, w1}, b2 = {w2, w2}, b3 = {w3, w3};
        floatx2 b4 = {w4, w4}, b5 = {w5, w5}, b6 = {w6, w6}, b7 = {w7, w7};
        pk_fma(a0, xp, b0); pk_fma(a1, xp, b1);
        pk_fma(a2, xp, b2); pk_fma(a3, xp, b3);
        pk_fma(a4, xp, b4); pk_fma(a5, xp, b5);
        pk_fma(a6, xp, b6); pk_fma(a7, xp, b7);
        touched = true;
      }
      if (touched) flush(d);
    }
  }
  __syncthreads();

  // ---- phase 2: normalize from LDS, per-head GEMM, bias + ELU, store ----
  {
    int quad = lane >> 4, l16 = lane & 15;
    int hp = w >> 1, q = w & 1;
    int h = w;                            // head handled by this wave's A-frag
    int d8 = l16 & 7;
    float invd = rcp_nr(DN[h * 8 + d8] + 1e-16f);
    floatx4 acc2[4] = {};
    const unsigned short* Bp = W1frag + (size_t)hp * 16384;
#pragma unroll
    for (int ks = 0; ks < 4; ++ks) {
      const float* ap = &AggF[(h * 8 + d8) * 132 + ks * 32 + quad * 8];
      float4 f0 = *(const float4*)ap;
      float4 f1 = *(const float4*)(ap + 4);
      union { short8 s; unsigned u[4]; } cv;
      cv.u[0] = pack2(f0.x * invd, f0.y * invd);
      cv.u[1] = pack2(f0.z * invd, f0.w * invd);
      cv.u[2] = pack2(f1.x * invd, f1.y * invd);
      cv.u[3] = pack2(f1.z * invd, f1.w * invd);
#pragma unroll
      for (int j = 0; j < 4; ++j) {
        int nt = q * 4 + j;
        short8 b = *(const short8*)&Bp[((nt * 4 + ks) * 64 + lane) * 8];
        acc2[j] = __builtin_amdgcn_mfma_f32_16x16x32_bf16(cv.s, b, acc2[j], 0, 0, 0);
      }
    }
    float4 bq = *(const float4*)&bias_perm[hp * 128 + l16 * 8 + q * 4];
#pragma unroll
    for (int r = 0; r < 4; ++r) {
      int dl = quad * 4 + r;              // C row; valid dests are rows 0..7
      int row = dbase + dl;
      if (dl < 8 && row < N) {
        uint2 o;
        o.x = pack2(elu1(acc2[0][r] + bq.x), elu1(acc2[1][r] + bq.y));
        o.y = pack2(elu1(acc2[2][r] + bq.z), elu1(acc2[3][r] + bq.w));
        *(uint2*)&out1[(size_t)row * 512 + hp * 128 + l16 * 8 + q * 4] = o;
      }
    }
  }
}

// ---------- layer 2: MFMA bf16 GEMM (k-dim permuted to match out1bf) ----------
__global__ __launch_bounds__(256) void gemm2_mfma_kernel(
    const unsigned short* __restrict__ x2bf,    // N x 512 bf16 (PERMUTED k)
    const unsigned short* __restrict__ W2frag,  // [16ks][4nt][64][8] bf16 (perm k)
    const float* __restrict__ att_src,          // 64
    const float* __restrict__ att_dst,
    unsigned short* __restrict__ h2,            // N x 64 bf16 (natural)
    float* __restrict__ a_s, float* __restrict__ a_d,  // N
    int N) {
  int t = threadIdx.x;
  int w = t >> 6, lane = t & 63;
  int quad = lane >> 4, l16 = lane & 15;
  int rowbase = blockIdx.x * 64 + w * 16;

  floatx4 acc[4] = {};
  int r0 = rowbase + l16; if (r0 >= N) r0 = N - 1;
  const unsigned short* p0 = x2bf + (size_t)r0 * 512 + quad * 8;
#pragma unroll
  for (int ks = 0; ks < 16; ++ks) {
    short8 a0 = *(const short8*)(p0 + ks * 32);
#pragma unroll
    for (int nt = 0; nt < 4; ++nt) {
      short8 b = *(const short8*)&W2frag[((ks * 4 + nt) * 64 + lane) * 8];
      acc[nt] = __builtin_amdgcn_mfma_f32_16x16x32_bf16(a0, b, acc[nt], 0, 0, 0);
    }
  }

  float asw[4], adw[4];
#pragma unroll
  for (int nt = 0; nt < 4; ++nt) {
    asw[nt] = att_src[nt * 16 + l16];
    adw[nt] = att_dst[nt * 16 + l16];
  }
  float ps[4] = {}, pd[4] = {};
#pragma unroll
  for (int nt = 0; nt < 4; ++nt)
#pragma unroll
    for (int r = 0; r < 4; ++r) {
      float v = acc[nt][r];
      int row = rowbase + quad * 4 + r;
      if (row < N) h2[(size_t)row * 64 + nt * 16 + l16] = f2bbits(v);
      ps[r] += v * asw[nt];
      pd[r] += v * adw[nt];
    }
#pragma unroll
  for (int r = 0; r < 4; ++r) {
    float p = ps[r], q = pd[r];
#pragma unroll
    for (int off = 1; off < 16; off <<= 1) {
      p += __shfl_xor(p, off);
      q += __shfl_xor(q, off);
    }
    int row = rowbase + quad * 4 + r;
    if (l16 == 0 && row < N) {
      a_s[row] = p;
      a_d[row] = q;
    }
  }
}

// H=1, quarter-wave edge grouping (h2 natural layout).
__global__ void gat_agg1_kernel(const int* __restrict__ rowptr,
                                const int* __restrict__ col,
                                const float* __restrict__ a_s,
                                const float* __restrict__ a_d,
                                const unsigned short* __restrict__ hfeat,
                                const float* __restrict__ bias,
                                unsigned short* __restrict__ out, int N) {
  int wave = threadIdx.x >> 6, lane = threadIdx.x & 63;
  int d = blockIdx.x * 4 + wave;
  if (d >= N) return;
  int beg = rowptr[d], end = rowptr[d + 1];
  int qg = lane >> 4, l16 = lane & 15;
  float adv = a_d[d];
  const uint2* hfu = (const uint2*)hfeat;
  float acc[4] = {};
  float wsum = 0.f;
#pragma unroll 2
  for (int i = beg + qg; i < end; i += 4) {
    int s = col[i];
    float v = a_s[s] + adv;
    v = v > 0.f ? v : NEG * v;
    float wv = __expf(v);
    wsum += wv;
    uint2 u = hfu[(size_t)s * 16 + l16];
    acc[0] += wv * blo(u.x); acc[1] += wv * bhi(u.x);
    acc[2] += wv * blo(u.y); acc[3] += wv * bhi(u.y);
  }
#pragma unroll
  for (int off = 16; off <= 32; off <<= 1) {
#pragma unroll
    for (int j = 0; j < 4; ++j) acc[j] += __shfl_xor(acc[j], off);
    wsum += __shfl_xor(wsum, off);
  }
  float winv = 1.f / (wsum + 1e-16f);
  float4 bb = ((const float4*)bias)[l16];
  float r0 = elu1(acc[0] * winv + bb.x), r1 = elu1(acc[1] * winv + bb.y);
  float r2 = elu1(acc[2] * winv + bb.z), r3 = elu1(acc[3] * winv + bb.w);
  if (qg == 0) {
    uint2 o; o.x = pack2(r0, r1); o.y = pack2(r2, r3);
    ((uint2*)out)[(size_t)d * 16 + l16] = o;
  }
}

// ---------- pooling: 16 nodes per wave ----------
__global__ void pool_kernel(const unsigned short* __restrict__ out2,
                            const int* __restrict__ batch,
                            float* __restrict__ pooled, int N) {
  int wave = threadIdx.x >> 6, lane = threadIdx.x & 63;
  int seg = blockIdx.x * 4 + wave;
  int start = seg * 16;
  if (start >= N) return;
  int end = min(start + 16, N);
  int cur = batch[start];
  float acc = 0.f;
  for (int n = start; n < end; ++n) {
    int bn = batch[n];
    if (bn != cur) {
      unsafeAtomicAdd(&pooled[cur * 64 + lane], acc);
      acc = 0.f; cur = bn;
    }
    acc += bu(out2[(size_t)n * 64 + lane]);
  }
  unsafeAtomicAdd(&pooled[cur * 64 + lane], acc);
}

// ---------- MLP head + log_softmax: one block (one wave) per graph ----------
__global__ void head_kernel(const float* __restrict__ pooled,
                            const float* __restrict__ lin1_w,
                            const float* __restrict__ lin1_b,
                            const float* __restrict__ lin2_w,
                            const float* __restrict__ lin2_b,
                            const void* __restrict__ x_raw,
                            void* __restrict__ outv) {
  __shared__ float P[C];
  __shared__ float Zs[C];
  __shared__ float Ls[K];
  __shared__ float lse_s;
  __shared__ int fl;
  int isbf = detect_dev(x_raw, &fl);
  int g = blockIdx.x, t = threadIdx.x;   // 64 threads
  P[t] = pooled[g * C + t];
  __syncthreads();
  float acc = lin1_b[t];
  for (int k = 0; k < C; ++k) acc += P[k] * lin1_w[k * C + t];
  Zs[t] = elu1(acc);
  __syncthreads();
  if (t < K) {
    float a = lin2_b[t];
    for (int k = 0; k < C; ++k) a += Zs[k] * lin2_w[k * K + t];
    Ls[t] = a;
  }
  __syncthreads();
  if (t == 0) {
    float mx = -1e30f;
    for (int c = 0; c < K; ++c) mx = fmaxf(mx, Ls[c]);
    float s = 0.f;
    for (int c = 0; c < K; ++c) s += __expf(Ls[c] - mx);
    lse_s = mx + __logf(s);
  }
  __syncthreads();
  if (t < K) {
    float val = Ls[t] - lse_s;
    if (isbf) ((__hip_bfloat16*)outv)[g * K + t] = __float2bfloat16(val);
    else      ((float*)outv)[g * K + t] = val;
  }
}

extern "C" void kernel_launch(void* const* d_in, const int* in_sizes, int n_in,
                              void* d_out, int out_size, void* d_ws, size_t ws_size,
                              hipStream_t stream) {
  const void* x_raw = d_in[0];
  const int*  ei    = (const int*)d_in[1];
  const int*  batch = (const int*)d_in[2];

  const int N    = in_sizes[2];
  const int E    = in_sizes[1] / 2;
  const int Etot = E + N;
  const int nb   = (N + 255) / 256;

  float* ws   = (float*)d_ws;
  size_t off  = 0;

  float* wts = ws + off; off += 6544;
  float* b1w  = wts + 1024;
  float* as2w = wts + 1536;
  float* ad2w = wts + 1600;
  float* b2w  = wts + 1664;
  float* l1w  = wts + 1728;
  float* l1b  = wts + 5824;
  float* l2w  = wts + 5888;
  float* l2b  = wts + 6528;

  unsigned short* xbf    = (unsigned short*)(ws + off); off += (size_t)N * 64;
  unsigned short* w1frag = (unsigned short*)(ws + off); off += 32768;
  unsigned short* w2frag = (unsigned short*)(ws + off); off += 16384;
  unsigned short* vfrag  = (unsigned short*)(ws + off); off += 1024;
  float* wedge           = ws + off;                    off += (size_t)Etot * 8;
  unsigned short* out1bf = (unsigned short*)(ws + off); off += (size_t)N * 256;
  unsigned short* h2bf   = (unsigned short*)(ws + off); off += (size_t)N * 32;
  unsigned short* out2bf = (unsigned short*)(ws + off); off += (size_t)N * 32;
  float* as1  = ws + off; off += (size_t)N * H1;
  float* ad1  = ws + off; off += (size_t)N * H1;
  float* as2  = ws + off; off += (size_t)N;
  float* ad2  = ws + off; off += (size_t)N;
  float* pooled = ws + off; off += (size_t)B * C;

  int* ibase  = (int*)(ws + off);
  int* deg    = ibase;                 ibase += N;
  int* cursor = ibase;                 ibase += N;
  int* rowptr = ibase;                 ibase += N + 1;
  int* locals = ibase;                 ibase += N;
  int* bsum   = ibase;                 ibase += 256;
  int* col    = ibase;                 ibase += Etot;

  // ---- prep ----
  fused_prep_kernel<<<1024, 256, 0, stream>>>(
      x_raw, d_in[3], d_in[4], d_in[5], d_in[6], d_in[7], d_in[8], d_in[9],
      d_in[10], d_in[11], d_in[12], d_in[13], d_in[14],
      xbf, w1frag, w2frag, vfrag, wts, deg, pooled, in_sizes[0], N);

  // ---- CSR: deg + scans ----
  deg_count_kernel<<<(Etot + 255) / 256, 256, 0, stream>>>(ei, E, Etot, deg);
  scan_block_kernel<<<nb, 256, 0, stream>>>(deg, locals, bsum, N);
  scan_finish_kernel<<<nb, 256, 0, stream>>>(locals, bsum, nb, rowptr, cursor, N, Etot);

  // ---- layer-1 attention scalars via factored V (tiny MFMA GEMM) ----
  att_scalars_kernel<<<(N + 63) / 64, 256, 0, stream>>>(xbf, vfrag, as1, ad1, N);

  // ---- CSR fill + per-edge softmax weights ----
  fill_weight_kernel<<<(Etot + 255) / 256, 256, 0, stream>>>(
      ei, E, Etot, as1, ad1, cursor, col, wedge);

  // ---- fused x-space aggregation + W1 GEMM -> out1 ----
  aggx_gemm1_kernel<<<(N + 7) / 8, 512, 0, stream>>>(
      xbf, w1frag, rowptr, col, wedge, b1w, out1bf, N);

  // ---- layer 2 ----
  gemm2_mfma_kernel<<<(N + 63) / 64, 256, 0, stream>>>(out1bf, w2frag, as2w, ad2w,
                                                       h2bf, as2, ad2, N);
  gat_agg1_kernel<<<(N + 3) / 4, 256, 0, stream>>>(rowptr, col, as2, ad2, h2bf, b2w, out2bf, N);

  // ---- pool + head ----
  pool_kernel<<<(N + 63) / 64, 256, 0, stream>>>(out2bf, batch, pooled, N);
  head_kernel<<<B, 64, 0, stream>>>(pooled, l1w, l1b, l2w, l2b, x_raw, (void*)d_out);
}

// Round 4
// 296.497 us; speedup vs baseline: 2.4467x; 2.4467x over previous
//
#include <hip/hip_runtime.h>
#include <hip/hip_bf16.h>

#define DEV static __device__ __forceinline__

constexpr int F1 = 128;   // input features
constexpr int H1 = 8;     // heads layer1
constexpr int C  = 64;    // channels per head
constexpr int B  = 64;    // graphs
constexpr int K  = 10;    // classes
constexpr float NEG = 0.2f;

typedef __attribute__((ext_vector_type(8))) short short8;
typedef __attribute__((ext_vector_type(4))) float floatx4;

DEV float b2f(__hip_bfloat16 x) { return __bfloat162float(x); }
DEV float elu1(float v) { return v > 0.f ? v : (__expf(v) - 1.f); }
DEV unsigned short f2bbits(float f) {
  __hip_bfloat16 b = __float2bfloat16(f);
  return *(unsigned short*)&b;
}
DEV float blo(unsigned u) { return __uint_as_float(u << 16); }
DEV float bhi(unsigned u) { return __uint_as_float(u & 0xffff0000u); }
DEV float bu(unsigned short u) { return __uint_as_float(((unsigned)u) << 16); }
DEV unsigned pack2(float lo, float hi) {
  return (unsigned)f2bbits(lo) | ((unsigned)f2bbits(hi) << 16);
}
// 1/x via v_rcp_f32 + one Newton step
DEV float rcp_nr(float x) {
  float r = __builtin_amdgcn_rcpf(x);
  return r * (2.f - x * r);
}

// out1 PERMUTED layout: position p = hp*128 + l16*8 + nt  <->  natural channel
// c = hp*128 + nt*16 + l16. W2frag k-rows and b1 permuted to match.
// W1frag k is NATURAL (round-1 layout).

// Self-detection: thread 0 samples 128 even-index bf16 reinterps of x.
DEV int detect_dev(const void* xraw, int* lds) {
  if (threadIdx.x == 0) {
    const __hip_bfloat16* xb = (const __hip_bfloat16*)xraw;
    int bad = 0;
    for (int i = 0; i < 128; ++i) {
      float v = b2f(xb[2 * i]);
      if (!(fabsf(v) < 1e4f)) bad++;
    }
    *lds = (bad < 13) ? 1 : 0;     // 1 = bf16, 0 = f32
  }
  __syncthreads();
  return *lds;
}

#define CVT(p, i) (isbf ? b2f(((const __hip_bfloat16*)(p))[i]) : ((const float*)(p))[i])

// ---------- fused prep ----------
__global__ void fused_prep_kernel(const void* x_raw, const void* w1raw,
                                  const void* as1r, const void* ad1r, const void* b1r,
                                  const void* w2raw,
                                  const void* as2r, const void* ad2r, const void* b2r,
                                  const void* l1wr, const void* l1br,
                                  const void* l2wr, const void* l2br,
                                  unsigned short* __restrict__ xbf,
                                  unsigned short* __restrict__ w1frag,
                                  unsigned short* __restrict__ w2frag,
                                  unsigned short* __restrict__ vfrag,
                                  float* __restrict__ wts,
                                  int* __restrict__ deg,
                                  float* __restrict__ pooled,
                                  int nX, int N) {
  __shared__ int fl;
  int isbf = detect_dev(x_raw, &fl);
  int gid = blockIdx.x * 256 + threadIdx.x;
  int stride = gridDim.x * 256;

  if (isbf) {
    const unsigned short* src = (const unsigned short*)x_raw;
    for (int i = gid; i < nX; i += stride) xbf[i] = src[i];
  } else {
    const float* src = (const float*)x_raw;
    for (int i = gid; i < nX; i += stride) xbf[i] = f2bbits(src[i]);
  }
  // b1 stored PERMUTED: wts[1024 + p] = b1[c_nat(p)]
  for (int i = gid; i < 512;  i += stride) {
    int hp = i >> 7, l16 = (i >> 3) & 15, nt = i & 7;
    int c = hp * 128 + nt * 16 + l16;
    wts[1024 + i] = CVT(b1r, c);
  }
  for (int i = gid; i < 64;   i += stride) wts[1536 + i] = CVT(as2r, i);
  for (int i = gid; i < 64;   i += stride) wts[1600 + i] = CVT(ad2r, i);
  for (int i = gid; i < 64;   i += stride) wts[1664 + i] = CVT(b2r, i);
  for (int i = gid; i < 4096; i += stride) wts[1728 + i] = CVT(l1wr, i);
  for (int i = gid; i < 64;   i += stride) wts[5824 + i] = CVT(l1br, i);
  for (int i = gid; i < 640;  i += stride) wts[5888 + i] = CVT(l2wr, i);
  for (int i = gid; i < 10;   i += stride) wts[6528 + i] = CVT(l2br, i);
  // W1frag NATURAL k
  for (int t = gid; t < 8192; t += stride) {
    int lane = t & 63, ks = (t >> 6) & 3, nt = t >> 8;
    for (int j = 0; j < 8; ++j) {
      int k = ks * 32 + (lane >> 4) * 8 + j;
      int n = nt * 16 + (lane & 15);
      w1frag[t * 8 + j] = f2bbits(CVT(w1raw, k * 512 + n));
    }
  }
  // W2frag with PERMUTED k: k index in fragment = position p; fetch W2[c_nat(p)]
  for (int t = gid; t < 4096; t += stride) {
    int lane = t & 63, nt = (t >> 6) & 3, ks = t >> 8;
    for (int j = 0; j < 8; ++j) {
      int p = ks * 32 + (lane >> 4) * 8 + j;          // permuted position
      int hp = p >> 7, pl16 = (p >> 3) & 15, pnt = p & 7;
      int k = hp * 128 + pnt * 16 + pl16;             // natural channel
      int n = nt * 16 + (lane & 15);
      w2frag[t * 8 + j] = f2bbits(CVT(w2raw, k * 64 + n));
    }
  }
  // Vfrag: B-fragment of V[128 x 16], V[:,n<8] = W1 head-n col @ att_src[n],
  // V[:,n>=8] = same with att_dst. a_s/a_d = x @ V.
  for (int t = gid; t < 2048; t += stride) {
    int j = t & 7, lane = (t >> 3) & 63, ks = t >> 9;
    int k = ks * 32 + (lane >> 4) * 8 + j;
    int n = lane & 15;
    int hh = (n < 8) ? n : (n - 8);
    float s = 0.f;
    if (n < 8) {
      for (int c = 0; c < 64; ++c)
        s += CVT(w1raw, k * 512 + hh * 64 + c) * CVT(as1r, hh * 64 + c);
    } else {
      for (int c = 0; c < 64; ++c)
        s += CVT(w1raw, k * 512 + hh * 64 + c) * CVT(ad1r, hh * 64 + c);
    }
    vfrag[(ks * 64 + lane) * 8 + j] = f2bbits(s);
  }
  for (int i = gid; i < N; i += stride) deg[i] = 0;
  for (int i = gid; i < B * C; i += stride) pooled[i] = 0.f;
}

// ---------- degree count ----------
__global__ void deg_count_kernel(const int* __restrict__ ei, int E, int Etot,
                                 int* __restrict__ deg) {
  int e = blockIdx.x * blockDim.x + threadIdx.x;
  if (e >= Etot) return;
  int d = (e < E) ? ei[E + e] : e - E;
  atomicAdd(&deg[d], 1);
}

// ---------- CSR scans ----------
__global__ void scan_block_kernel(const int* __restrict__ deg,
                                  int* __restrict__ local,
                                  int* __restrict__ bsum, int N) {
  __shared__ int tmp[256];
  int t = threadIdx.x;
  int i = blockIdx.x * 256 + t;
  int v = (i < N) ? deg[i] : 0;
  tmp[t] = v;
  __syncthreads();
  for (int off = 1; off < 256; off <<= 1) {
    int u = (t >= off) ? tmp[t - off] : 0;
    __syncthreads();
    tmp[t] += u;
    __syncthreads();
  }
  if (i < N) local[i] = tmp[t] - v;
  if (t == 255) bsum[blockIdx.x] = tmp[255];
}

__global__ void scan_finish_kernel(const int* __restrict__ local,
                                   const int* __restrict__ bsum, int nb,
                                   int* __restrict__ rowptr,
                                   int* __restrict__ cursor, int N, int Etot) {
  __shared__ int tmp[256];
  __shared__ int offs;
  int t = threadIdx.x;
  int v0 = (t < nb) ? bsum[t] : 0;
  tmp[t] = v0;
  __syncthreads();
  for (int off = 1; off < 256; off <<= 1) {
    int u = (t >= off) ? tmp[t - off] : 0;
    __syncthreads();
    tmp[t] += u;
    __syncthreads();
  }
  if (t == (int)blockIdx.x) offs = tmp[t] - v0;
  __syncthreads();
  int i = blockIdx.x * 256 + t;
  if (i < N) {
    int r = local[i] + offs;
    rowptr[i] = r;
    cursor[i] = r;
  }
  if (i == 0) rowptr[N] = Etot;
}

// ---------- attention scalars: a_s/a_d = x @ V  (4 MFMA per 16 rows) ----------
__global__ __launch_bounds__(256) void att_scalars_kernel(
    const unsigned short* __restrict__ xbf,     // N x 128 bf16
    const unsigned short* __restrict__ vfrag,   // [4ks][64][8] bf16
    float* __restrict__ a_s, float* __restrict__ a_d,   // N x 8
    int N) {
  int t = threadIdx.x, w = t >> 6, lane = t & 63;
  int quad = lane >> 4, l16 = lane & 15;
  int row0 = blockIdx.x * 64 + w * 16;

  floatx4 acc = {};
  int rl = row0 + l16; if (rl >= N) rl = N - 1;
  const unsigned short* xp = xbf + (size_t)rl * 128 + quad * 8;
#pragma unroll
  for (int ks = 0; ks < 4; ++ks) {
    short8 a = *(const short8*)(xp + ks * 32);
    short8 b = *(const short8*)&vfrag[(ks * 64 + lane) * 8];
    acc = __builtin_amdgcn_mfma_f32_16x16x32_bf16(a, b, acc, 0, 0, 0);
  }
#pragma unroll
  for (int r = 0; r < 4; ++r) {
    int row = row0 + quad * 4 + r;
    if (row < N) {
      if (l16 < 8) a_s[(size_t)row * 8 + l16] = acc[r];
      else         a_d[(size_t)row * 8 + (l16 - 8)] = acc[r];
    }
  }
}

// ---------- CSR fill + per-edge softmax weights (f32, CSR slot order) ----------
__global__ void fill_weight_kernel(const int* __restrict__ ei, int E, int Etot,
                                   const float* __restrict__ a_s,
                                   const float* __restrict__ a_d,
                                   int* __restrict__ cursor,
                                   int* __restrict__ col,
                                   float* __restrict__ wedge) {
  int e = blockIdx.x * 256 + threadIdx.x;
  if (e >= Etot) return;
  int s, d;
  if (e < E) { s = ei[e]; d = ei[E + e]; } else { s = d = e - E; }
  int pos = atomicAdd(&cursor[d], 1);
  col[pos] = s;
  float4 s0 = *(const float4*)(a_s + (size_t)s * 8);
  float4 s1 = *(const float4*)(a_s + (size_t)s * 8 + 4);
  float4 d0 = *(const float4*)(a_d + (size_t)d * 8);
  float4 d1 = *(const float4*)(a_d + (size_t)d * 8 + 4);
  float4 w0, w1;
  float v;
  v = s0.x + d0.x; v = v > 0.f ? v : NEG * v; w0.x = __expf(v);
  v = s0.y + d0.y; v = v > 0.f ? v : NEG * v; w0.y = __expf(v);
  v = s0.z + d0.z; v = v > 0.f ? v : NEG * v; w0.z = __expf(v);
  v = s0.w + d0.w; v = v > 0.f ? v : NEG * v; w0.w = __expf(v);
  v = s1.x + d1.x; v = v > 0.f ? v : NEG * v; w1.x = __expf(v);
  v = s1.y + d1.y; v = v > 0.f ? v : NEG * v; w1.y = __expf(v);
  v = s1.z + d1.z; v = v > 0.f ? v : NEG * v; w1.z = __expf(v);
  v = s1.w + d1.w; v = v > 0.f ? v : NEG * v; w1.w = __expf(v);
  *(float4*)(wedge + (size_t)pos * 8)     = w0;
  *(float4*)(wedge + (size_t)pos * 8 + 4) = w1;
}

// ---------- MFMA-based x-space aggregation + W1 GEMM -> out1 ----------
// Block = 512 threads (8 waves), TILE = 16 dests. The tile's contiguous CSR
// range is processed in chunks of 32 edge slots:
//   stage XgT[128f][32k] bf16 (transposed gather, XOR-swizzled banks)
//   build Wm[8h][16d][32k] bf16 masked weights (full recompute, no barrier #3)
//   wave h: accw[ft] += MFMA(Wm[h], XgT[ft]); accdn += MFMA(Wm[h], ones)
// Denominator = ones-column MFMA (col 0 of accdn). Epilogue: normalize, write
// AggP[8h][16d][128] bf16, then per-head [16x128]@[128x512] W1 MFMA GEMM.
__global__ __launch_bounds__(512, 4) void aggx_gemm1_kernel(
    const unsigned short* __restrict__ xbf,     // N x 128 bf16
    const unsigned short* __restrict__ W1frag,  // [32][4][64][8] bf16 (natural k)
    const int* __restrict__ rowptr,
    const int* __restrict__ col,
    const float* __restrict__ wedge,            // Etot x 8 f32 (CSR order)
    const float* __restrict__ bias_perm,        // 512, PERMUTED
    unsigned short* __restrict__ out1,          // N x 512 bf16 (PERMUTED)
    int N) {
  __shared__ __align__(16) unsigned short XgT[128 * 32];      // 8 KB
  __shared__ __align__(16) unsigned short Wm[8 * 16 * 32];    // 8 KB
  __shared__ __align__(16) unsigned short AggP[8 * 16 * 136]; // 34.8 KB
  __shared__ int rpl[17];

  int t = threadIdx.x, w = t >> 6, lane = t & 63;
  int q = lane >> 4, n = lane & 15;
  int dbase = blockIdx.x * 16;

  if (t < 17) rpl[t] = rowptr[min(dbase + t, N)];
  __syncthreads();
  int R0 = rpl[0], R1 = rpl[16];
  int nch = (R1 - R0 + 31) >> 5;

  // staging ids
  int ke = t >> 4, p = t & 15;
  // wmat ids
  int dw = t >> 5, kw = t & 31;

  // ones B-fragment: B[k][n] = (n==0) ? 1.0bf16 : 0
  short8 onesf = {};
  if (n == 0) {
#pragma unroll
    for (int j = 0; j < 8; ++j) onesf[j] = (short)0x3F80;
  }

  floatx4 accw[8] = {};
  floatx4 accdn = {};

  for (int c = 0; c < nch; ++c) {
    int ebase = R0 + c * 32;
    __syncthreads();                       // prior chunk's MFMA reads done

    // ---- stage XgT (transposed, swizzled) ----
    {
      int e = ebase + ke;
      int ec = (e < R1) ? e : (R1 - 1);
      int s = col[ec];
      uint4 xv = *(const uint4*)(xbf + (size_t)s * 128 + p * 8);
      int xb = (512 * p + 2 * ke) ^ ((p & 3) << 4);
      unsigned short* xp0 = (unsigned short*)((char*)XgT + xb);
      xp0[0]   = (unsigned short)(xv.x & 0xffff);
      xp0[32]  = (unsigned short)(xv.x >> 16);
      xp0[64]  = (unsigned short)(xv.y & 0xffff);
      xp0[96]  = (unsigned short)(xv.y >> 16);
      xp0[128] = (unsigned short)(xv.z & 0xffff);
      xp0[160] = (unsigned short)(xv.z >> 16);
      xp0[192] = (unsigned short)(xv.w & 0xffff);
      xp0[224] = (unsigned short)(xv.w >> 16);
    }
    // ---- build Wm (full recompute: each thread owns (dw, kw)) ----
    {
      int ew = ebase + kw;
      bool evw = ew < R1;
      int ewc = evw ? ew : (R1 - 1);
      int dl = 0;
#pragma unroll
      for (int b = 8; b; b >>= 1) dl += (rpl[dl + b] <= ew) ? b : 0;
      float4 wa = *(const float4*)(wedge + (size_t)ewc * 8);
      float4 wb = *(const float4*)(wedge + (size_t)ewc * 8 + 4);
      bool mine = evw && (dl == dw);
      unsigned short z = 0;
      unsigned short* wmp = Wm + dw * 32 + kw;
      wmp[0]    = mine ? f2bbits(wa.x) : z;
      wmp[512]  = mine ? f2bbits(wa.y) : z;
      wmp[1024] = mine ? f2bbits(wa.z) : z;
      wmp[1536] = mine ? f2bbits(wa.w) : z;
      wmp[2048] = mine ? f2bbits(wb.x) : z;
      wmp[2560] = mine ? f2bbits(wb.y) : z;
      wmp[3072] = mine ? f2bbits(wb.z) : z;
      wmp[3584] = mine ? f2bbits(wb.w) : z;
    }
    __syncthreads();

    // ---- MFMA: wave w = head w ----
    short8 af = *(const short8*)(Wm + w * 512 + n * 32 + 8 * q);
    accdn = __builtin_amdgcn_mfma_f32_16x16x32_bf16(af, onesf, accdn, 0, 0, 0);
#pragma unroll
    for (int ft = 0; ft < 8; ++ft) {
      int bb = (ft * 16 + n) * 64 + 16 * q;
      bb ^= ((bb >> 9) & 3) << 4;
      short8 bfr = *(const short8*)((const char*)XgT + bb);
      accw[ft] = __builtin_amdgcn_mfma_f32_16x16x32_bf16(af, bfr, accw[ft], 0, 0, 0);
    }
  }

  // ---- epilogue: normalize, write AggP[h][d][f] bf16 ----
  {
    float dnv[4];
#pragma unroll
    for (int r = 0; r < 4; ++r) {
      float dr = __shfl(accdn[r], lane & 48);      // broadcast col-0 lane of quad
      dnv[r] = rcp_nr(dr + 1e-16f);
    }
#pragma unroll
    for (int ft = 0; ft < 8; ++ft)
#pragma unroll
      for (int r = 0; r < 4; ++r)
        AggP[w * 2176 + (4 * q + r) * 136 + ft * 16 + n] =
            f2bbits(accw[ft][r] * dnv[r]);
  }
  __syncthreads();

  // ---- phase 3: per-head W1 GEMM, bias + ELU, permuted store ----
  {
    int hp = w >> 1, qq = w & 1;
    floatx4 acc2[4] = {};
    const unsigned short* Bp = W1frag + (size_t)hp * 16384;
#pragma unroll
    for (int ks = 0; ks < 4; ++ks) {
      short8 a2 = *(const short8*)&AggP[w * 2176 + n * 136 + ks * 32 + q * 8];
#pragma unroll
      for (int j = 0; j < 4; ++j) {
        int nt = qq * 4 + j;
        short8 b2 = *(const short8*)&Bp[((nt * 4 + ks) * 64 + lane) * 8];
        acc2[j] = __builtin_amdgcn_mfma_f32_16x16x32_bf16(a2, b2, acc2[j], 0, 0, 0);
      }
    }
    float4 bq = *(const float4*)&bias_perm[hp * 128 + n * 8 + qq * 4];
#pragma unroll
    for (int r = 0; r < 4; ++r) {
      int row = dbase + 4 * q + r;
      if (row < N) {
        uint2 o;
        o.x = pack2(elu1(acc2[0][r] + bq.x), elu1(acc2[1][r] + bq.y));
        o.y = pack2(elu1(acc2[2][r] + bq.z), elu1(acc2[3][r] + bq.w));
        *(uint2*)&out1[(size_t)row * 512 + hp * 128 + n * 8 + qq * 4] = o;
      }
    }
  }
}

// ---------- layer 2: MFMA bf16 GEMM (k-dim permuted to match out1bf) ----------
__global__ __launch_bounds__(256) void gemm2_mfma_kernel(
    const unsigned short* __restrict__ x2bf,    // N x 512 bf16 (PERMUTED k)
    const unsigned short* __restrict__ W2frag,  // [16ks][4nt][64][8] bf16 (perm k)
    const float* __restrict__ att_src,          // 64
    const float* __restrict__ att_dst,
    unsigned short* __restrict__ h2,            // N x 64 bf16 (natural)
    float* __restrict__ a_s, float* __restrict__ a_d,  // N
    int N) {
  int t = threadIdx.x;
  int w = t >> 6, lane = t & 63;
  int quad = lane >> 4, l16 = lane & 15;
  int rowbase = blockIdx.x * 64 + w * 16;

  floatx4 acc[4] = {};
  int r0 = rowbase + l16; if (r0 >= N) r0 = N - 1;
  const unsigned short* p0 = x2bf + (size_t)r0 * 512 + quad * 8;
#pragma unroll
  for (int ks = 0; ks < 16; ++ks) {
    short8 a0 = *(const short8*)(p0 + ks * 32);
#pragma unroll
    for (int nt = 0; nt < 4; ++nt) {
      short8 b = *(const short8*)&W2frag[((ks * 4 + nt) * 64 + lane) * 8];
      acc[nt] = __builtin_amdgcn_mfma_f32_16x16x32_bf16(a0, b, acc[nt], 0, 0, 0);
    }
  }

  float asw[4], adw[4];
#pragma unroll
  for (int nt = 0; nt < 4; ++nt) {
    asw[nt] = att_src[nt * 16 + l16];
    adw[nt] = att_dst[nt * 16 + l16];
  }
  float ps[4] = {}, pd[4] = {};
#pragma unroll
  for (int nt = 0; nt < 4; ++nt)
#pragma unroll
    for (int r = 0; r < 4; ++r) {
      float v = acc[nt][r];
      int row = rowbase + quad * 4 + r;
      if (row < N) h2[(size_t)row * 64 + nt * 16 + l16] = f2bbits(v);
      ps[r] += v * asw[nt];
      pd[r] += v * adw[nt];
    }
#pragma unroll
  for (int r = 0; r < 4; ++r) {
    float p = ps[r], q = pd[r];
#pragma unroll
    for (int off = 1; off < 16; off <<= 1) {
      p += __shfl_xor(p, off);
      q += __shfl_xor(q, off);
    }
    int row = rowbase + quad * 4 + r;
    if (l16 == 0 && row < N) {
      a_s[row] = p;
      a_d[row] = q;
    }
  }
}

// H=1, quarter-wave edge grouping (h2 natural layout).
__global__ void gat_agg1_kernel(const int* __restrict__ rowptr,
                                const int* __restrict__ col,
                                const float* __restrict__ a_s,
                                const float* __restrict__ a_d,
                                const unsigned short* __restrict__ hfeat,
                                const float* __restrict__ bias,
                                unsigned short* __restrict__ out, int N) {
  int wave = threadIdx.x >> 6, lane = threadIdx.x & 63;
  int d = blockIdx.x * 4 + wave;
  if (d >= N) return;
  int beg = rowptr[d], end = rowptr[d + 1];
  int qg = lane >> 4, l16 = lane & 15;
  float adv = a_d[d];
  const uint2* hfu = (const uint2*)hfeat;
  float acc[4] = {};
  float wsum = 0.f;
#pragma unroll 2
  for (int i = beg + qg; i < end; i += 4) {
    int s = col[i];
    float v = a_s[s] + adv;
    v = v > 0.f ? v : NEG * v;
    float wv = __expf(v);
    wsum += wv;
    uint2 u = hfu[(size_t)s * 16 + l16];
    acc[0] += wv * blo(u.x); acc[1] += wv * bhi(u.x);
    acc[2] += wv * blo(u.y); acc[3] += wv * bhi(u.y);
  }
#pragma unroll
  for (int off = 16; off <= 32; off <<= 1) {
#pragma unroll
    for (int j = 0; j < 4; ++j) acc[j] += __shfl_xor(acc[j], off);
    wsum += __shfl_xor(wsum, off);
  }
  float winv = 1.f / (wsum + 1e-16f);
  float4 bb = ((const float4*)bias)[l16];
  float r0 = elu1(acc[0] * winv + bb.x), r1 = elu1(acc[1] * winv + bb.y);
  float r2 = elu1(acc[2] * winv + bb.z), r3 = elu1(acc[3] * winv + bb.w);
  if (qg == 0) {
    uint2 o; o.x = pack2(r0, r1); o.y = pack2(r2, r3);
    ((uint2*)out)[(size_t)d * 16 + l16] = o;
  }
}

// ---------- pooling: 16 nodes per wave ----------
__global__ void pool_kernel(const unsigned short* __restrict__ out2,
                            const int* __restrict__ batch,
                            float* __restrict__ pooled, int N) {
  int wave = threadIdx.x >> 6, lane = threadIdx.x & 63;
  int seg = blockIdx.x * 4 + wave;
  int start = seg * 16;
  if (start >= N) return;
  int end = min(start + 16, N);
  int cur = batch[start];
  float acc = 0.f;
  for (int n = start; n < end; ++n) {
    int bn = batch[n];
    if (bn != cur) {
      unsafeAtomicAdd(&pooled[cur * 64 + lane], acc);
      acc = 0.f; cur = bn;
    }
    acc += bu(out2[(size_t)n * 64 + lane]);
  }
  unsafeAtomicAdd(&pooled[cur * 64 + lane], acc);
}

// ---------- MLP head + log_softmax: one block (one wave) per graph ----------
__global__ void head_kernel(const float* __restrict__ pooled,
                            const float* __restrict__ lin1_w,
                            const float* __restrict__ lin1_b,
                            const float* __restrict__ lin2_w,
                            const float* __restrict__ lin2_b,
                            const void* __restrict__ x_raw,
                            void* __restrict__ outv) {
  __shared__ float P[C];
  __shared__ float Zs[C];
  __shared__ float Ls[K];
  __shared__ float lse_s;
  __shared__ int fl;
  int isbf = detect_dev(x_raw, &fl);
  int g = blockIdx.x, t = threadIdx.x;   // 64 threads
  P[t] = pooled[g * C + t];
  __syncthreads();
  float acc = lin1_b[t];
  for (int k = 0; k < C; ++k) acc += P[k] * lin1_w[k * C + t];
  Zs[t] = elu1(acc);
  __syncthreads();
  if (t < K) {
    float a = lin2_b[t];
    for (int k = 0; k < C; ++k) a += Zs[k] * lin2_w[k * K + t];
    Ls[t] = a;
  }
  __syncthreads();
  if (t == 0) {
    float mx = -1e30f;
    for (int c = 0; c < K; ++c) mx = fmaxf(mx, Ls[c]);
    float s = 0.f;
    for (int c = 0; c < K; ++c) s += __expf(Ls[c] - mx);
    lse_s = mx + __logf(s);
  }
  __syncthreads();
  if (t < K) {
    float val = Ls[t] - lse_s;
    if (isbf) ((__hip_bfloat16*)outv)[g * K + t] = __float2bfloat16(val);
    else      ((float*)outv)[g * K + t] = val;
  }
}

extern "C" void kernel_launch(void* const* d_in, const int* in_sizes, int n_in,
                              void* d_out, int out_size, void* d_ws, size_t ws_size,
                              hipStream_t stream) {
  const void* x_raw = d_in[0];
  const int*  ei    = (const int*)d_in[1];
  const int*  batch = (const int*)d_in[2];

  const int N    = in_sizes[2];
  const int E    = in_sizes[1] / 2;
  const int Etot = E + N;
  const int nb   = (N + 255) / 256;

  float* ws   = (float*)d_ws;
  size_t off  = 0;

  float* wts = ws + off; off += 6544;
  float* b1w  = wts + 1024;
  float* as2w = wts + 1536;
  float* ad2w = wts + 1600;
  float* b2w  = wts + 1664;
  float* l1w  = wts + 1728;
  float* l1b  = wts + 5824;
  float* l2w  = wts + 5888;
  float* l2b  = wts + 6528;

  unsigned short* xbf    = (unsigned short*)(ws + off); off += (size_t)N * 64;
  unsigned short* w1frag = (unsigned short*)(ws + off); off += 32768;
  unsigned short* w2frag = (unsigned short*)(ws + off); off += 16384;
  unsigned short* vfrag  = (unsigned short*)(ws + off); off += 1024;
  float* wedge           = ws + off;                    off += (size_t)Etot * 8;
  unsigned short* out1bf = (unsigned short*)(ws + off); off += (size_t)N * 256;
  unsigned short* h2bf   = (unsigned short*)(ws + off); off += (size_t)N * 32;
  unsigned short* out2bf = (unsigned short*)(ws + off); off += (size_t)N * 32;
  float* as1  = ws + off; off += (size_t)N * H1;
  float* ad1  = ws + off; off += (size_t)N * H1;
  float* as2  = ws + off; off += (size_t)N;
  float* ad2  = ws + off; off += (size_t)N;
  float* pooled = ws + off; off += (size_t)B * C;

  int* ibase  = (int*)(ws + off);
  int* deg    = ibase;                 ibase += N;
  int* cursor = ibase;                 ibase += N;
  int* rowptr = ibase;                 ibase += N + 1;
  int* locals = ibase;                 ibase += N;
  int* bsum   = ibase;                 ibase += 256;
  int* col    = ibase;                 ibase += Etot;

  // ---- prep ----
  fused_prep_kernel<<<1024, 256, 0, stream>>>(
      x_raw, d_in[3], d_in[4], d_in[5], d_in[6], d_in[7], d_in[8], d_in[9],
      d_in[10], d_in[11], d_in[12], d_in[13], d_in[14],
      xbf, w1frag, w2frag, vfrag, wts, deg, pooled, in_sizes[0], N);

  // ---- CSR: deg + scans ----
  deg_count_kernel<<<(Etot + 255) / 256, 256, 0, stream>>>(ei, E, Etot, deg);
  scan_block_kernel<<<nb, 256, 0, stream>>>(deg, locals, bsum, N);
  scan_finish_kernel<<<nb, 256, 0, stream>>>(locals, bsum, nb, rowptr, cursor, N, Etot);

  // ---- layer-1 attention scalars via factored V (tiny MFMA GEMM) ----
  att_scalars_kernel<<<(N + 63) / 64, 256, 0, stream>>>(xbf, vfrag, as1, ad1, N);

  // ---- CSR fill + per-edge softmax weights ----
  fill_weight_kernel<<<(Etot + 255) / 256, 256, 0, stream>>>(
      ei, E, Etot, as1, ad1, cursor, col, wedge);

  // ---- MFMA x-space aggregation + W1 GEMM -> out1 ----
  aggx_gemm1_kernel<<<(N + 15) / 16, 512, 0, stream>>>(
      xbf, w1frag, rowptr, col, wedge, b1w, out1bf, N);

  // ---- layer 2 ----
  gemm2_mfma_kernel<<<(N + 63) / 64, 256, 0, stream>>>(out1bf, w2frag, as2w, ad2w,
                                                       h2bf, as2, ad2, N);
  gat_agg1_kernel<<<(N + 3) / 4, 256, 0, stream>>>(rowptr, col, as2, ad2, h2bf, b2w, out2bf, N);

  // ---- pool + head ----
  pool_kernel<<<(N + 63) / 64, 256, 0, stream>>>(out2bf, batch, pooled, N);
  head_kernel<<<B, 64, 0, stream>>>(pooled, l1w, l1b, l2w, l2b, x_raw, (void*)d_out);
}